// Round 1
// baseline (1057.166 us; speedup 1.0000x reference)
//
#include <hip/hip_runtime.h>
#include <math.h>

#define NTN 32768      // total nodes
#define NBG 32         // batch (graphs)
#define NN  1024       // nodes per graph
#define EE  262144     // edges
#define FIN 64
#define HIDC 128
#define HD  4
#define HC  512        // HD*HIDC
#define EDIM 16
#define NR  16
#define KP1 820
#define KP2 656
#define NEGS 0.2f

// ---------------- node GEMM: C[NTN,512] = A[NTN,K] @ W[K,512] + b ----------------
template<int K>
__global__ __launch_bounds__(256) void gemm_node(const float* __restrict__ A,
                                                 const float* __restrict__ W,
                                                 const float* __restrict__ b,
                                                 float* __restrict__ C) {
    __shared__ float a_s[8][K];
    int t = threadIdx.x;
    int row0 = blockIdx.x * 8;
    for (int i = t; i < 8 * K; i += 256) a_s[i / K][i % K] = A[(size_t)(row0 + i / K) * K + (i % K)];
    __syncthreads();
    int c0 = t, c1 = t + 256;
    float acc[8][2];
    float bb0 = b[c0], bb1 = b[c1];
    #pragma unroll
    for (int r = 0; r < 8; r++) { acc[r][0] = bb0; acc[r][1] = bb1; }
    for (int k = 0; k < K; k++) {
        float w0 = W[(size_t)k * HC + c0], w1 = W[(size_t)k * HC + c1];
        #pragma unroll
        for (int r = 0; r < 8; r++) { float a = a_s[r][k]; acc[r][0] += a * w0; acc[r][1] += a * w1; }
    }
    for (int r = 0; r < 8; r++) {
        C[(size_t)(row0 + r) * HC + c0] = acc[r][0];
        C[(size_t)(row0 + r) * HC + c1] = acc[r][1];
    }
}

// ---------------- edge CSR build ----------------
__global__ void edge_hist(const int* __restrict__ dst, int* __restrict__ deg) {
    int e = blockIdx.x * 256 + threadIdx.x;
    if (e < EE) atomicAdd(&deg[dst[e]], 1);
}

__global__ __launch_bounds__(1024) void scan_deg(const int* __restrict__ deg,
                                                 int* __restrict__ off, int* __restrict__ cur) {
    __shared__ int s[1024];
    int t = threadIdx.x;
    int base = t * 32;
    int local[32];
    int sum = 0;
    #pragma unroll
    for (int i = 0; i < 32; i++) { local[i] = deg[base + i]; sum += local[i]; }
    s[t] = sum;
    for (int o = 1; o < 1024; o <<= 1) {
        __syncthreads();
        int v = (t >= o) ? s[t - o] : 0;
        __syncthreads();
        s[t] += v;
    }
    __syncthreads();
    int run = s[t] - sum;  // exclusive prefix of this chunk
    #pragma unroll
    for (int i = 0; i < 32; i++) { off[base + i] = run; cur[base + i] = run; run += local[i]; }
    if (t == 1023) off[NTN] = EE;
}

__global__ void edge_scatter(const int* __restrict__ dst, int* __restrict__ cur,
                             int* __restrict__ ebuf) {
    int e = blockIdx.x * 256 + threadIdx.x;
    if (e < EE) { int p = atomicAdd(&cur[dst[e]], 1); ebuf[p] = e; }
}

// ---------------- fused GATv2 per-dst (online softmax) ----------------
__global__ __launch_bounds__(256) void gat_dst(
        const float* __restrict__ xl, const float* __restrict__ xr,
        const float* __restrict__ ea, const float* __restrict__ We,
        const float* __restrict__ att, const float* __restrict__ bias,
        const int* __restrict__ srcArr, const int* __restrict__ ebuf,
        const int* __restrict__ off, const int* __restrict__ keep,
        float* __restrict__ out) {
    int d = blockIdx.x;
    int t = threadIdx.x;
    __shared__ float red[HC];
    __shared__ float eaS[EDIM];
    __shared__ float logitS[HD];
    int c0 = t, c1 = t + 256;
    float we0[EDIM], we1[EDIM];
    #pragma unroll
    for (int k = 0; k < EDIM; k++) { we0[k] = We[(size_t)k * HC + c0]; we1[k] = We[(size_t)k * HC + c1]; }
    float at0 = att[c0], at1 = att[c1];
    float xr0 = xr[(size_t)d * HC + c0], xr1 = xr[(size_t)d * HC + c1];
    int e0 = off[d], e1 = off[d + 1];
    bool dk = keep ? (keep[d] != 0) : true;
    float m0 = -3e38f, m1 = -3e38f, den0 = 0.f, den1 = 0.f, acc0 = 0.f, acc1 = 0.f;
    int h0 = t >> 7;  // head of c0; head of c1 = h0+2
    if (dk) {
        for (int ei = e0; ei < e1; ei++) {
            int e = ebuf[ei];
            int s = srcArr[e];
            if (keep && !keep[s]) continue;   // uniform across block
            __syncthreads();
            if (t < EDIM) eaS[t] = ea[(size_t)e * EDIM + t];
            __syncthreads();
            float ef0 = 0.f, ef1 = 0.f;
            #pragma unroll
            for (int k = 0; k < EDIM; k++) { float a = eaS[k]; ef0 += a * we0[k]; ef1 += a * we1[k]; }
            float xl0 = xl[(size_t)s * HC + c0], xl1 = xl[(size_t)s * HC + c1];
            float v0 = xl0 + xr0 + ef0, v1 = xl1 + xr1 + ef1;
            v0 = v0 > 0.f ? v0 : NEGS * v0;
            v1 = v1 > 0.f ? v1 : NEGS * v1;
            red[c0] = v0 * at0;
            red[c1] = v1 * at1;
            __syncthreads();
            int lane = t & 63, w = t >> 6;
            float pv = red[w * HIDC + lane] + red[w * HIDC + lane + 64];
            #pragma unroll
            for (int sft = 32; sft; sft >>= 1) pv += __shfl_xor(pv, sft, 64);
            if (lane == 0) logitS[w] = pv;
            __syncthreads();
            float l0 = logitS[h0], l1 = logitS[h0 + 2];
            // online softmax, head of c0
            float nm0 = fmaxf(m0, l0);
            float so0 = expf(m0 - nm0), w0 = expf(l0 - nm0);
            den0 = den0 * so0 + w0;
            acc0 = acc0 * so0 + w0 * xl0;
            m0 = nm0;
            // head of c1
            float nm1 = fmaxf(m1, l1);
            float so1 = expf(m1 - nm1), w1 = expf(l1 - nm1);
            den1 = den1 * so1 + w1;
            acc1 = acc1 * so1 + w1 * xl1;
            m1 = nm1;
        }
    }
    __syncthreads();
    red[c0] = acc0 / (den0 + 1e-16f);
    red[c1] = acc1 / (den1 + 1e-16f);
    __syncthreads();
    if (t < HIDC) {
        float v = (red[t] + red[t + 128] + red[t + 256] + red[t + 384]) * 0.25f + bias[t];
        out[(size_t)d * HIDC + t] = fmaxf(v, 0.f);
    }
}

// ---------------- pooling: score, gate-scale, top-k ----------------
__global__ __launch_bounds__(256) void score_gate(const float* __restrict__ h,
                                                  const float* __restrict__ p,
                                                  float* __restrict__ score) {
    __shared__ float pS[HIDC];
    __shared__ float pn;
    int t = threadIdx.x;
    if (t < HIDC) pS[t] = p[t];
    __syncthreads();
    if (t == 0) {
        float s = 0.f;
        for (int i = 0; i < HIDC; i++) s += pS[i] * pS[i];
        pn = sqrtf(s);
    }
    __syncthreads();
    int n = blockIdx.x * 256 + t;
    const float* hr = h + (size_t)n * HIDC;
    float s = 0.f;
    for (int i = 0; i < HIDC; i++) s += hr[i] * pS[i];
    score[n] = s / (pn + 1e-16f);
}

__global__ void gate_scale(float* __restrict__ h, const float* __restrict__ score) {
    int i = blockIdx.x * 256 + threadIdx.x;
    h[i] *= tanhf(score[i >> 7]);
}

__global__ __launch_bounds__(512) void topk_sel(const float* __restrict__ score,
                                                const int* __restrict__ mask, int k,
                                                int* __restrict__ keep) {
    __shared__ float v[NN];
    __shared__ short id[NN];
    int g = blockIdx.x, t = threadIdx.x;
    for (int i = t; i < NN; i += 512) {
        int n = g * NN + i;
        bool mk = mask ? (mask[n] != 0) : true;
        v[i] = mk ? score[n] : -INFINITY;
        id[i] = (short)i;
    }
    __syncthreads();
    for (int kk = 2; kk <= NN; kk <<= 1) {
        for (int j = kk >> 1; j > 0; j >>= 1) {
            #pragma unroll 2
            for (int i = t; i < NN; i += 512) {
                int ixj = i ^ j;
                if (ixj > i) {
                    bool up = ((i & kk) == 0);
                    float a = v[i], b2 = v[ixj];
                    short ia = id[i], ib = id[ixj];
                    bool aFirst = (a > b2) || (a == b2 && ia < ib);
                    if (up ? !aFirst : aFirst) { v[i] = b2; v[ixj] = a; id[i] = ib; id[ixj] = ia; }
                }
            }
            __syncthreads();
        }
    }
    for (int i = t; i < NN; i += 512) keep[g * NN + id[i]] = (i < k) ? 1 : 0;
}

// ---------------- global pool + MLP ----------------
__global__ __launch_bounds__(128) void gpool(const float* __restrict__ h,
                                             const int* __restrict__ keep,
                                             const float* __restrict__ action,
                                             float* __restrict__ z) {
    int g = blockIdx.x, c = threadIdx.x;
    float mx = -INFINITY, sm = 0.f;
    for (int n = 0; n < NN; n++) {
        if (keep[g * NN + n]) {
            float v = h[(size_t)(g * NN + n) * HIDC + c];
            mx = fmaxf(mx, v);
            sm += v;
        }
    }
    z[g * 272 + c] = mx;
    z[g * 272 + 128 + c] = sm / (float)KP2;
    if (c < NR) z[g * 272 + 256 + c] = action[g * NR + c];
}

__global__ __launch_bounds__(128) void mlp(const float* __restrict__ z,
                                           const float* __restrict__ Wf1, const float* __restrict__ bf1,
                                           const float* __restrict__ Wf2, const float* __restrict__ bf2,
                                           const float* __restrict__ Wf3, const float* __restrict__ bf3,
                                           float* __restrict__ out) {
    int g = blockIdx.x, t = threadIdx.x;
    __shared__ float zs[272], z1[HIDC], z2[HIDC], r[HIDC];
    for (int i = t; i < 272; i += 128) zs[i] = z[g * 272 + i];
    __syncthreads();
    float a = bf1[t];
    for (int k = 0; k < 272; k++) a += zs[k] * Wf1[(size_t)k * HIDC + t];
    z1[t] = fmaxf(a, 0.f);
    __syncthreads();
    a = bf2[t];
    for (int k = 0; k < HIDC; k++) a += z1[k] * Wf2[(size_t)k * HIDC + t];
    z2[t] = fmaxf(a, 0.f);
    __syncthreads();
    r[t] = z2[t] * Wf3[t];
    __syncthreads();
    for (int s = 64; s; s >>= 1) { if (t < s) r[t] += r[t + s]; __syncthreads(); }
    if (t == 0) out[g] = r[0] + bf3[0];
}

extern "C" void kernel_launch(void* const* d_in, const int* in_sizes, int n_in,
                              void* d_out, int out_size, void* d_ws, size_t ws_size,
                              hipStream_t stream) {
    const float* x    = (const float*)d_in[0];
    const float* ea   = (const float*)d_in[1];
    const float* act  = (const float*)d_in[2];
    const float* W1l  = (const float*)d_in[3];
    const float* b1l  = (const float*)d_in[4];
    const float* W1r  = (const float*)d_in[5];
    const float* b1r  = (const float*)d_in[6];
    const float* W1e  = (const float*)d_in[7];
    const float* att1 = (const float*)d_in[8];
    const float* bias1= (const float*)d_in[9];
    const float* W2l  = (const float*)d_in[10];
    const float* b2l  = (const float*)d_in[11];
    const float* W2r  = (const float*)d_in[12];
    const float* b2r  = (const float*)d_in[13];
    const float* W2e  = (const float*)d_in[14];
    const float* att2 = (const float*)d_in[15];
    const float* bias2= (const float*)d_in[16];
    const float* p1   = (const float*)d_in[17];
    const float* p2   = (const float*)d_in[18];
    const float* Wf1  = (const float*)d_in[19];
    const float* bf1  = (const float*)d_in[20];
    const float* Wf2  = (const float*)d_in[21];
    const float* bf2  = (const float*)d_in[22];
    const float* Wf3  = (const float*)d_in[23];
    const float* bf3  = (const float*)d_in[24];
    const int*   eix  = (const int*)d_in[25];
    const int* srcA = eix;
    const int* dstA = eix + EE;

    float* ws   = (float*)d_ws;
    float* xl   = ws;
    float* xr   = xl + (size_t)NTN * HC;
    float* h    = xr + (size_t)NTN * HC;
    float* score= h + (size_t)NTN * HIDC;
    float* zbuf = score + NTN;
    int* keep1  = (int*)(zbuf + NBG * 272);
    int* keep2  = keep1 + NTN;
    int* deg    = keep2 + NTN;
    int* off    = deg + NTN;
    int* cur    = off + NTN + 1;
    int* ebuf   = cur + NTN;

    // ---- edge CSR (dst-sorted) ----
    hipMemsetAsync(deg, 0, NTN * sizeof(int), stream);
    edge_hist<<<EE / 256, 256, 0, stream>>>(dstA, deg);
    scan_deg<<<1, 1024, 0, stream>>>(deg, off, cur);
    edge_scatter<<<EE / 256, 256, 0, stream>>>(dstA, cur, ebuf);

    // ---- layer 1 ----
    gemm_node<FIN><<<NTN / 8, 256, 0, stream>>>(x, W1l, b1l, xl);
    gemm_node<FIN><<<NTN / 8, 256, 0, stream>>>(x, W1r, b1r, xr);
    gat_dst<<<NTN, 256, 0, stream>>>(xl, xr, ea, W1e, att1, bias1, srcA, ebuf, off, nullptr, h);

    // ---- pool 1 ----
    score_gate<<<NTN / 256, 256, 0, stream>>>(h, p1, score);
    topk_sel<<<NBG, 512, 0, stream>>>(score, nullptr, KP1, keep1);
    gate_scale<<<(NTN * HIDC) / 256, 256, 0, stream>>>(h, score);

    // ---- layer 2 ----
    gemm_node<HIDC><<<NTN / 8, 256, 0, stream>>>(h, W2l, b2l, xl);
    gemm_node<HIDC><<<NTN / 8, 256, 0, stream>>>(h, W2r, b2r, xr);
    gat_dst<<<NTN, 256, 0, stream>>>(xl, xr, ea, W2e, att2, bias2, srcA, ebuf, off, keep1, h);

    // ---- pool 2 ----
    score_gate<<<NTN / 256, 256, 0, stream>>>(h, p2, score);
    topk_sel<<<NBG, 512, 0, stream>>>(score, keep1, KP2, keep2);
    gate_scale<<<(NTN * HIDC) / 256, 256, 0, stream>>>(h, score);

    // ---- global pool + MLP ----
    gpool<<<NBG, 128, 0, stream>>>(h, keep2, act, zbuf);
    mlp<<<NBG, 128, 0, stream>>>(zbuf, Wf1, bf1, Wf2, bf2, Wf3, bf3, (float*)d_out);
}

// Round 2
// 640.189 us; speedup vs baseline: 1.6513x; 1.6513x over previous
//
#include <hip/hip_runtime.h>
#include <math.h>

#define NTN 32768      // total nodes
#define NBG 32         // batch (graphs)
#define NN  1024       // nodes per graph
#define EE  262144     // edges
#define FIN 64
#define HIDC 128
#define HD  4
#define HC  512        // HD*HIDC
#define EDIM 16
#define NR  16
#define KP1 820
#define KP2 656
#define NEGS 0.2f

// ---------------- node GEMM: C[NTN,512] = (A*gate)[NTN,K] @ W[K,512] + b ----------------
template<int K>
__global__ __launch_bounds__(256) void gemm_node(const float* __restrict__ A,
                                                 const float* __restrict__ W,
                                                 const float* __restrict__ b,
                                                 const float* __restrict__ gs,
                                                 float* __restrict__ C) {
    __shared__ float a_s[K][16];
    __shared__ float g_s[16];
    int t = threadIdx.x;
    int row0 = blockIdx.x * 16;
    if (t < 16) g_s[t] = gs ? tanhf(gs[row0 + t]) : 1.0f;
    __syncthreads();
    for (int i = t; i < 16 * K; i += 256) {
        int r = i / K, k = i % K;
        a_s[k][r] = A[(size_t)(row0 + r) * K + k] * g_s[r];
    }
    __syncthreads();
    int c0 = t, c1 = t + 256;
    float acc0[16], acc1[16];
    float bb0 = b[c0], bb1 = b[c1];
    #pragma unroll
    for (int r = 0; r < 16; r++) { acc0[r] = bb0; acc1[r] = bb1; }
    for (int k = 0; k < K; k++) {
        float w0 = W[(size_t)k * HC + c0], w1 = W[(size_t)k * HC + c1];
        const float4* ap = (const float4*)&a_s[k][0];
        float4 A0 = ap[0], A1 = ap[1], A2 = ap[2], A3 = ap[3];
        float av[16] = {A0.x, A0.y, A0.z, A0.w, A1.x, A1.y, A1.z, A1.w,
                        A2.x, A2.y, A2.z, A2.w, A3.x, A3.y, A3.z, A3.w};
        #pragma unroll
        for (int r = 0; r < 16; r++) { acc0[r] += av[r] * w0; acc1[r] += av[r] * w1; }
    }
    for (int r = 0; r < 16; r++) {
        C[(size_t)(row0 + r) * HC + c0] = acc0[r];
        C[(size_t)(row0 + r) * HC + c1] = acc1[r];
    }
}

// ---------------- edge CSR build (optionally keep-filtered) ----------------
__global__ void edge_hist(const int* __restrict__ dst, const int* __restrict__ src,
                          const int* __restrict__ keep, int* __restrict__ deg) {
    int e = blockIdx.x * 256 + threadIdx.x;
    if (e < EE) {
        if (keep && (!keep[src[e]] || !keep[dst[e]])) return;
        atomicAdd(&deg[dst[e]], 1);
    }
}

__global__ __launch_bounds__(1024) void scan_deg(const int* __restrict__ deg,
                                                 int* __restrict__ off, int* __restrict__ cur) {
    __shared__ int s[1024];
    int t = threadIdx.x;
    int base = t * 32;
    int local[32];
    int sum = 0;
    #pragma unroll
    for (int i = 0; i < 32; i++) { local[i] = deg[base + i]; sum += local[i]; }
    s[t] = sum;
    for (int o = 1; o < 1024; o <<= 1) {
        __syncthreads();
        int v = (t >= o) ? s[t - o] : 0;
        __syncthreads();
        s[t] += v;
    }
    __syncthreads();
    int run = s[t] - sum;  // exclusive prefix of this chunk
    #pragma unroll
    for (int i = 0; i < 32; i++) { off[base + i] = run; cur[base + i] = run; run += local[i]; }
    if (t == 1023) off[NTN] = s[1023];
}

__global__ void edge_scatter(const int* __restrict__ dst, const int* __restrict__ src,
                             const int* __restrict__ keep, int* __restrict__ cur,
                             int* __restrict__ ebuf, int* __restrict__ esrc) {
    int e = blockIdx.x * 256 + threadIdx.x;
    if (e < EE) {
        if (keep && (!keep[src[e]] || !keep[dst[e]])) return;
        int p = atomicAdd(&cur[dst[e]], 1);
        ebuf[p] = e;
        esrc[p] = src[e];
    }
}

// ---------------- fused GATv2 per-dst: wave-per-head online softmax ----------------
__global__ __launch_bounds__(256) void gat_dst(
        const float* __restrict__ xl, const float* __restrict__ xr,
        const float* __restrict__ ea, const float* __restrict__ We,
        const float* __restrict__ att, const float* __restrict__ bias,
        const int* __restrict__ ebuf, const int* __restrict__ esrc,
        const int* __restrict__ off,
        float* __restrict__ out) {
    int d = blockIdx.x;
    int t = threadIdx.x;
    int w = t >> 6, lane = t & 63;
    int c = w * HIDC + lane * 2;         // 2 channels of head w
    float we0[EDIM], we1[EDIM];
    #pragma unroll
    for (int k = 0; k < EDIM; k++) {
        we0[k] = We[(size_t)k * HC + c];
        we1[k] = We[(size_t)k * HC + c + 1];
    }
    float at0 = att[c], at1 = att[c + 1];
    float2 xrv = *(const float2*)&xr[(size_t)d * HC + c];
    int e0 = off[d], e1 = off[d + 1];
    float m = -3e38f, den = 0.f, acc0 = 0.f, acc1 = 0.f;
    for (int ei = e0; ei < e1; ei++) {
        int e = ebuf[ei];
        int s = esrc[ei];
        const float4* eap = (const float4*)(ea + (size_t)e * EDIM);
        float4 E0 = eap[0], E1 = eap[1], E2 = eap[2], E3 = eap[3];
        float2 xlv = *(const float2*)&xl[(size_t)s * HC + c];
        float ev[16] = {E0.x, E0.y, E0.z, E0.w, E1.x, E1.y, E1.z, E1.w,
                        E2.x, E2.y, E2.z, E2.w, E3.x, E3.y, E3.z, E3.w};
        float ef0 = 0.f, ef1 = 0.f;
        #pragma unroll
        for (int k = 0; k < EDIM; k++) { ef0 += ev[k] * we0[k]; ef1 += ev[k] * we1[k]; }
        float v0 = xlv.x + xrv.x + ef0; v0 = v0 > 0.f ? v0 : NEGS * v0;
        float v1 = xlv.y + xrv.y + ef1; v1 = v1 > 0.f ? v1 : NEGS * v1;
        float p = v0 * at0 + v1 * at1;
        #pragma unroll
        for (int sft = 32; sft; sft >>= 1) p += __shfl_xor(p, sft, 64);
        // p = head-w logit, uniform across wave
        if (p > m) {
            float sc = __expf(m - p);           // first edge: exp(-huge)=0
            den = den * sc + 1.f;
            acc0 = acc0 * sc + xlv.x;
            acc1 = acc1 * sc + xlv.y;
            m = p;
        } else {
            float wt = __expf(p - m);
            den += wt;
            acc0 += wt * xlv.x;
            acc1 += wt * xlv.y;
        }
    }
    __shared__ float red[HC];
    float inv = 1.f / (den + 1e-16f);
    red[c] = acc0 * inv;
    red[c + 1] = acc1 * inv;
    __syncthreads();
    if (t < HIDC) {
        float v = (red[t] + red[t + 128] + red[t + 256] + red[t + 384]) * 0.25f + bias[t];
        out[(size_t)d * HIDC + t] = fmaxf(v, 0.f);
    }
}

// ---------------- pooling: score (coalesced, wave-per-node), top-k ----------------
__global__ __launch_bounds__(256) void score_nodes(const float* __restrict__ h,
                                                   const float* __restrict__ p,
                                                   float* __restrict__ score) {
    __shared__ float pS[HIDC];
    __shared__ float invn;
    int t = threadIdx.x;
    if (t < HIDC) pS[t] = p[t];
    __syncthreads();
    if (t == 0) {
        float s = 0.f;
        for (int i = 0; i < HIDC; i++) s += pS[i] * pS[i];
        invn = 1.f / (sqrtf(s) + 1e-16f);
    }
    __syncthreads();
    int w = t >> 6, lane = t & 63;
    float p0 = pS[lane * 2], p1 = pS[lane * 2 + 1];
    float iv = invn;
    for (int j = 0; j < 8; j++) {
        int n = blockIdx.x * 32 + w * 8 + j;
        float2 hv = *(const float2*)&h[(size_t)n * HIDC + lane * 2];
        float v = hv.x * p0 + hv.y * p1;
        #pragma unroll
        for (int sft = 32; sft; sft >>= 1) v += __shfl_xor(v, sft, 64);
        if (lane == 0) score[n] = v * iv;
    }
}

__global__ __launch_bounds__(512) void topk_sel(const float* __restrict__ score,
                                                const int* __restrict__ mask, int k,
                                                int* __restrict__ keep) {
    __shared__ float v[NN];
    __shared__ short id[NN];
    int g = blockIdx.x, t = threadIdx.x;
    for (int i = t; i < NN; i += 512) {
        int n = g * NN + i;
        bool mk = mask ? (mask[n] != 0) : true;
        v[i] = mk ? score[n] : -INFINITY;
        id[i] = (short)i;
    }
    __syncthreads();
    for (int kk = 2; kk <= NN; kk <<= 1) {
        for (int j = kk >> 1; j > 0; j >>= 1) {
            #pragma unroll 2
            for (int i = t; i < NN; i += 512) {
                int ixj = i ^ j;
                if (ixj > i) {
                    bool up = ((i & kk) == 0);
                    float a = v[i], b2 = v[ixj];
                    short ia = id[i], ib = id[ixj];
                    bool aFirst = (a > b2) || (a == b2 && ia < ib);
                    if (up ? !aFirst : aFirst) { v[i] = b2; v[ixj] = a; id[i] = ib; id[ixj] = ia; }
                }
            }
            __syncthreads();
        }
    }
    for (int i = t; i < NN; i += 512) keep[g * NN + id[i]] = (i < k) ? 1 : 0;
}

// ---------------- global pool (gate fused) + MLP ----------------
__global__ __launch_bounds__(512) void gpool(const float* __restrict__ h,
                                             const int* __restrict__ keep,
                                             const float* __restrict__ score,
                                             const float* __restrict__ action,
                                             float* __restrict__ z) {
    int g = blockIdx.x, t = threadIdx.x;
    int c = t & 127, ch = t >> 7;    // 4 chunks of 256 nodes
    __shared__ float gt_s[NN];
    __shared__ char kp_s[NN];
    __shared__ float smx[4][HIDC], ssm[4][HIDC];
    for (int i = t; i < NN; i += 512) {
        int n = g * NN + i;
        int kk = keep[n];
        kp_s[i] = (char)kk;
        gt_s[i] = kk ? tanhf(score[n]) : 0.f;
    }
    __syncthreads();
    float mx = -INFINITY, sm = 0.f;
    for (int n = ch * 256; n < ch * 256 + 256; n++) {
        if (kp_s[n]) {
            float v = h[(size_t)(g * NN + n) * HIDC + c] * gt_s[n];
            mx = fmaxf(mx, v);
            sm += v;
        }
    }
    smx[ch][c] = mx; ssm[ch][c] = sm;
    __syncthreads();
    if (t < HIDC) {
        mx = fmaxf(fmaxf(smx[0][t], smx[1][t]), fmaxf(smx[2][t], smx[3][t]));
        sm = ssm[0][t] + ssm[1][t] + ssm[2][t] + ssm[3][t];
        z[g * 272 + t] = mx;
        z[g * 272 + 128 + t] = sm / (float)KP2;
        if (t < NR) z[g * 272 + 256 + t] = action[g * NR + t];
    }
}

__global__ __launch_bounds__(128) void mlp(const float* __restrict__ z,
                                           const float* __restrict__ Wf1, const float* __restrict__ bf1,
                                           const float* __restrict__ Wf2, const float* __restrict__ bf2,
                                           const float* __restrict__ Wf3, const float* __restrict__ bf3,
                                           float* __restrict__ out) {
    int g = blockIdx.x, t = threadIdx.x;
    __shared__ float zs[272], z1[HIDC], z2[HIDC], r[HIDC];
    for (int i = t; i < 272; i += 128) zs[i] = z[g * 272 + i];
    __syncthreads();
    float a = bf1[t];
    for (int k = 0; k < 272; k++) a += zs[k] * Wf1[(size_t)k * HIDC + t];
    z1[t] = fmaxf(a, 0.f);
    __syncthreads();
    a = bf2[t];
    for (int k = 0; k < HIDC; k++) a += z1[k] * Wf2[(size_t)k * HIDC + t];
    z2[t] = fmaxf(a, 0.f);
    __syncthreads();
    r[t] = z2[t] * Wf3[t];
    __syncthreads();
    for (int s = 64; s; s >>= 1) { if (t < s) r[t] += r[t + s]; __syncthreads(); }
    if (t == 0) out[g] = r[0] + bf3[0];
}

extern "C" void kernel_launch(void* const* d_in, const int* in_sizes, int n_in,
                              void* d_out, int out_size, void* d_ws, size_t ws_size,
                              hipStream_t stream) {
    const float* x    = (const float*)d_in[0];
    const float* ea   = (const float*)d_in[1];
    const float* act  = (const float*)d_in[2];
    const float* W1l  = (const float*)d_in[3];
    const float* b1l  = (const float*)d_in[4];
    const float* W1r  = (const float*)d_in[5];
    const float* b1r  = (const float*)d_in[6];
    const float* W1e  = (const float*)d_in[7];
    const float* att1 = (const float*)d_in[8];
    const float* bias1= (const float*)d_in[9];
    const float* W2l  = (const float*)d_in[10];
    const float* b2l  = (const float*)d_in[11];
    const float* W2r  = (const float*)d_in[12];
    const float* b2r  = (const float*)d_in[13];
    const float* W2e  = (const float*)d_in[14];
    const float* att2 = (const float*)d_in[15];
    const float* bias2= (const float*)d_in[16];
    const float* p1   = (const float*)d_in[17];
    const float* p2   = (const float*)d_in[18];
    const float* Wf1  = (const float*)d_in[19];
    const float* bf1  = (const float*)d_in[20];
    const float* Wf2  = (const float*)d_in[21];
    const float* bf2  = (const float*)d_in[22];
    const float* Wf3  = (const float*)d_in[23];
    const float* bf3  = (const float*)d_in[24];
    const int*   eix  = (const int*)d_in[25];
    const int* srcA = eix;
    const int* dstA = eix + EE;

    float* ws    = (float*)d_ws;
    float* xl    = ws;
    float* xr    = xl + (size_t)NTN * HC;
    float* h     = xr + (size_t)NTN * HC;
    float* score1= h + (size_t)NTN * HIDC;
    float* score2= score1 + NTN;
    float* zbuf  = score2 + NTN;
    int* keep1 = (int*)(zbuf + NBG * 272);
    int* keep2 = keep1 + NTN;
    int* deg   = keep2 + NTN;
    int* off   = deg + NTN;
    int* cur   = off + NTN + 1;
    int* ebuf  = cur + NTN;
    int* esrc  = ebuf + EE;
    int* deg2  = esrc + EE;
    int* off2  = deg2 + NTN;
    int* cur2  = off2 + NTN + 1;
    int* ebuf2 = cur2 + NTN;
    int* esrc2 = ebuf2 + EE;

    // ---- CSR layer 1 (all edges) ----
    hipMemsetAsync(deg, 0, NTN * sizeof(int), stream);
    edge_hist<<<EE / 256, 256, 0, stream>>>(dstA, srcA, nullptr, deg);
    scan_deg<<<1, 1024, 0, stream>>>(deg, off, cur);
    edge_scatter<<<EE / 256, 256, 0, stream>>>(dstA, srcA, nullptr, cur, ebuf, esrc);

    // ---- layer 1 ----
    gemm_node<FIN><<<NTN / 16, 256, 0, stream>>>(x, W1l, b1l, nullptr, xl);
    gemm_node<FIN><<<NTN / 16, 256, 0, stream>>>(x, W1r, b1r, nullptr, xr);
    gat_dst<<<NTN, 256, 0, stream>>>(xl, xr, ea, W1e, att1, bias1, ebuf, esrc, off, h);

    // ---- pool 1 ----
    score_nodes<<<NTN / 32, 256, 0, stream>>>(h, p1, score1);
    topk_sel<<<NBG, 512, 0, stream>>>(score1, nullptr, KP1, keep1);

    // ---- CSR layer 2 (live edges only) ----
    hipMemsetAsync(deg2, 0, NTN * sizeof(int), stream);
    edge_hist<<<EE / 256, 256, 0, stream>>>(dstA, srcA, keep1, deg2);
    scan_deg<<<1, 1024, 0, stream>>>(deg2, off2, cur2);
    edge_scatter<<<EE / 256, 256, 0, stream>>>(dstA, srcA, keep1, cur2, ebuf2, esrc2);

    // ---- layer 2 (gate of pool1 fused into GEMM staging) ----
    gemm_node<HIDC><<<NTN / 16, 256, 0, stream>>>(h, W2l, b2l, score1, xl);
    gemm_node<HIDC><<<NTN / 16, 256, 0, stream>>>(h, W2r, b2r, score1, xr);
    gat_dst<<<NTN, 256, 0, stream>>>(xl, xr, ea, W2e, att2, bias2, ebuf2, esrc2, off2, h);

    // ---- pool 2 ----
    score_nodes<<<NTN / 32, 256, 0, stream>>>(h, p2, score2);
    topk_sel<<<NBG, 512, 0, stream>>>(score2, keep1, KP2, keep2);

    // ---- global pool (gate2 fused) + MLP ----
    gpool<<<NBG, 512, 0, stream>>>(h, keep2, score2, act, zbuf);
    mlp<<<NBG, 128, 0, stream>>>(zbuf, Wf1, bf1, Wf2, bf2, Wf3, bf3, (float*)d_out);
}